// Round 1
// 765.910 us; speedup vs baseline: 1.0892x; 1.0892x over previous
//
#include <hip/hip_runtime.h>

// SequentialChart: ops < START(256) => steps independent. Algebraic cut:
// PL[b,op]=U_left@h(b,op), PR[b,op]=U_right@h(b,op) (16x fewer FLOPs),
// preact = PL[opL]+PR[opR] (bias folded into PL at GEMM epilogue).
// log2e folded into U/bias at cvt time: gates use raw v_exp_f32 (exp2).
// GEMM: m97 structure -- 128x128 tile, BK=64, global_load_lds w=16 with
// pre-swizzled source, 32 MFMA + 16 ds_read_b128 per K-step.
// Fused gates+softmax+combine: c in 64KB LDS, h in packed-bf16 regs,
// cross-wave h-reduction through reused LDS -> 2 blocks/CU.

typedef unsigned int u32;
typedef unsigned short u16;
typedef __attribute__((ext_vector_type(8))) short short8;
typedef __attribute__((ext_vector_type(4))) float f32x4;
typedef __attribute__((ext_vector_type(4))) u16 u16x4;
typedef __attribute__((ext_vector_type(8))) u16 u16x8;
typedef _Float16 h8 __attribute__((ext_vector_type(8)));

#define CHART_ROWS 384
#define L2E 1.4426950408889634f

__device__ __forceinline__ u16 f2bf(float f) {           // fp32 -> bf16 RNE
  u32 u = __float_as_uint(f);
  u32 r = u + 0x7fffu + ((u >> 16) & 1u);
  return (u16)(r >> 16);
}
__device__ __forceinline__ float bf2f(u16 v) { return __uint_as_float(((u32)v) << 16); }
// preact pre-scaled by -log2e: sigmoid(x) = 1/(1+2^(-x*log2e))
__device__ __forceinline__ float sig2(float p) {
  return __builtin_amdgcn_rcpf(1.0f + __builtin_amdgcn_exp2f(p));
}
// preact pre-scaled by +2*log2e: tanh(x) = 1 - 2/(1+2^(2x*log2e))
__device__ __forceinline__ float tanh2(float p) {
  return 1.0f - 2.0f * __builtin_amdgcn_rcpf(1.0f + __builtin_amdgcn_exp2f(p));
}
// runtime-argument tanh (for tanh(c)); compiler folds 2*log2e into one mul
__device__ __forceinline__ float fast_tanh(float x) {
  return 1.0f - 2.0f * __builtin_amdgcn_rcpf(1.0f + __builtin_amdgcn_exp2f(2.0f * L2E * x));
}

__device__ __forceinline__ void async16(const void* g, void* l) {
  __builtin_amdgcn_global_load_lds((const __attribute__((address_space(1))) u32*)g,
                                   (__attribute__((address_space(3))) u32*)l, 16, 0, 0);
}

// ---- U (5120x2048 fp32) -> bf16, scaled by -log2e (sigmoid rows) / +2log2e (u rows)
__global__ void k_cvt_u(const float4* __restrict__ U4, u16* __restrict__ Ubf) {
  int i = blockIdx.x * blockDim.x + threadIdx.x;   // 2,621,440 threads
  int row = i >> 9;                                // 512 float4 per 2048-col row
  float sc = (row < 4096) ? -L2E : (2.0f * L2E);
  float4 v = U4[i];
  u16x4 o = {f2bf(v.x * sc), f2bf(v.y * sc), f2bf(v.z * sc), f2bf(v.w * sc)};
  *(u16x4*)(Ubf + (size_t)i * 4) = o;
}

// ---- chart rows<256: h-half -> chb, c-half -> chc; also copy rows<256 to out
__global__ void k_cvt_chart(const float* __restrict__ chart,
                            u16* __restrict__ chb, u16* __restrict__ chc,
                            float* __restrict__ out) {
  int i = blockIdx.x * blockDim.x + threadIdx.x;   // 2,097,152 threads
  int row = i >> 8;                 // b*256 + op, < 8192
  int k4 = (i & 255) * 4;
  int b = row >> 8, op = row & 255;
  const size_t base = (size_t)(b * CHART_ROWS + op) * 2048;
  const float4 vh = *(const float4*)(chart + base + 1024 + k4);
  const float4 vc = *(const float4*)(chart + base + k4);
  u16x4 oh = {f2bf(vh.x), f2bf(vh.y), f2bf(vh.z), f2bf(vh.w)};
  u16x4 oc = {f2bf(vc.x), f2bf(vc.y), f2bf(vc.z), f2bf(vc.w)};
  *(u16x4*)(chb + (size_t)row * 1024 + k4) = oh;
  *(u16x4*)(chc + (size_t)row * 1024 + k4) = oc;
  *(float4*)(out + base + k4) = vc;          // rows < 256 pass through
  *(float4*)(out + base + 1024 + k4) = vh;   // rows >= 256 written by k_fused
}

// ---- P[half][bo][G] = sum_k chb[bg*2048+bo][k] * U[G][half*1024+k] (+bias on half0)
// m97 structure: 128x128 tile, BK=64, 2 barriers per K-step, 16 K-steps.
__global__ __launch_bounds__(256, 2) void k_gemm_p(
    const u16* __restrict__ chb, const u16* __restrict__ Ubf,
    const float* __restrict__ bias, _Float16* __restrict__ P, int bg)
{
  __shared__ u16 As[128 * 64];   // 16 KB
  __shared__ u16 Bs[128 * 64];   // 16 KB
  const int tid = threadIdx.x;
  const int wave = tid >> 6, lane = tid & 63;
  const int lane15 = lane & 15, quad = lane >> 4;
  const int bx = blockIdx.x;        // G tile (0..39)
  const int by = blockIdx.y;        // 0..31
  const int half = by >> 4;
  const int rt = by & 15;           // row tile within half

  // staging: 4 rounds per matrix; LDS chunk idx = rnd*256+tid, 16B each.
  // chunk (row r, slot s) holds global col-chunk c = s ^ (r&7)  (pre-swizzled src)
  const u16* aSrc[4]; const u16* bSrc[4];
  u16* aDst[4]; u16* bDst[4];
#pragma unroll
  for (int rnd = 0; rnd < 4; ++rnd) {
    int idx = rnd * 256 + tid;
    int r = idx >> 3, s = idx & 7;
    int c = s ^ (r & 7);
    aSrc[rnd] = chb + (size_t)(bg * 2048 + rt * 128 + r) * 1024 + c * 8;
    aDst[rnd] = As + (size_t)idx * 8;
    bSrc[rnd] = Ubf + (size_t)(bx * 128 + r) * 2048 + half * 1024 + c * 8;
    bDst[rnd] = Bs + (size_t)idx * 8;
  }

  // fragment read offsets: row m, want col-chunk (kk*4+quad) -> slot = c ^ (m&7)
  int aOff[4][2], bOff[4][2];
#pragma unroll
  for (int mt = 0; mt < 4; ++mt) {
    int m = (wave & 1) * 64 + mt * 16 + lane15;
#pragma unroll
    for (int kk = 0; kk < 2; ++kk)
      aOff[mt][kk] = m * 64 + (((kk * 4 + quad) ^ (m & 7)) * 8);
  }
#pragma unroll
  for (int gt = 0; gt < 4; ++gt) {
    int g = (wave >> 1) * 64 + gt * 16 + lane15;
#pragma unroll
    for (int kk = 0; kk < 2; ++kk)
      bOff[gt][kk] = g * 64 + (((kk * 4 + quad) ^ (g & 7)) * 8);
  }

  const f32x4 zero4 = {0.f, 0.f, 0.f, 0.f};
  f32x4 acc[4][4];
#pragma unroll
  for (int mt = 0; mt < 4; ++mt)
#pragma unroll
    for (int gt = 0; gt < 4; ++gt) acc[mt][gt] = zero4;

  for (int ko = 0; ko < 1024; ko += 64) {
    __syncthreads();
#pragma unroll
    for (int rnd = 0; rnd < 4; ++rnd) {
      async16(aSrc[rnd] + ko, aDst[rnd]);
      async16(bSrc[rnd] + ko, bDst[rnd]);
    }
    __syncthreads();
    short8 af[4][2], bfr[4][2];
#pragma unroll
    for (int mt = 0; mt < 4; ++mt)
#pragma unroll
      for (int kk = 0; kk < 2; ++kk) af[mt][kk] = *(const short8*)(As + aOff[mt][kk]);
#pragma unroll
    for (int gt = 0; gt < 4; ++gt)
#pragma unroll
      for (int kk = 0; kk < 2; ++kk) bfr[gt][kk] = *(const short8*)(Bs + bOff[gt][kk]);
#pragma unroll
    for (int kk = 0; kk < 2; ++kk)
#pragma unroll
      for (int mt = 0; mt < 4; ++mt)
#pragma unroll
        for (int gt = 0; gt < 4; ++gt)
          acc[mt][gt] = __builtin_amdgcn_mfma_f32_16x16x32_bf16(af[mt][kk], bfr[gt][kk], acc[mt][gt], 0, 0, 0);
  }

  float bb[4];   // bias folded into half 0 only, scaled like U rows
#pragma unroll
  for (int gt = 0; gt < 4; ++gt) {
    int g = bx * 128 + (wave >> 1) * 64 + gt * 16 + lane15;
    float sc = (g < 4096) ? -L2E : (2.0f * L2E);
    bb[gt] = (half == 0) ? bias[g] * sc : 0.f;
  }

#pragma unroll
  for (int mt = 0; mt < 4; ++mt)
#pragma unroll
    for (int rg = 0; rg < 4; ++rg) {
      int row = (wave & 1) * 64 + mt * 16 + quad * 4 + rg;
      size_t pbase = (size_t)(half * 2048 + rt * 128 + row) * 5120 + bx * 128 + (wave >> 1) * 64;
#pragma unroll
      for (int gt = 0; gt < 4; ++gt)
        P[pbase + gt * 16 + lane15] = (_Float16)(acc[mt][gt][rg] + bb[gt]);
    }
}

// ---- fused: gather-add preact + gates + energy + softmax + combine ----
// Block = (step, b_local) via 1-D grid with XCD-affine b (flat&7).
// 512 thr = 8 waves; wave w handles rows a = t*8+w, lane owns cols l*16..+16.
// c -> LDS (permuted, 64KB); h -> 32 packed-bf16 VGPRs; h combined via
// cross-wave partial reduction through the reused LDS buffer.
__global__ __launch_bounds__(512, 4) void k_fused(
    const u16* __restrict__ chc, const _Float16* __restrict__ P,
    const int* __restrict__ ops, const float* __restrict__ eu,
    float* __restrict__ out, int bg)
{
  __shared__ u16 cS[32 * 1024];   // 64 KB; reused as float[8*1024] for h-reduce
  __shared__ float eS[32];

  const int tid = threadIdx.x;
  const int wave = tid >> 6, lane = tid & 63;
  const int flat = blockIdx.x;
  const int b_local = flat & 7;     // XCD-affine: same-XCD blocks share b
  const int step = flat >> 3;
  const int b = bg * 8 + b_local;

  float ureg[16];
  *(float4*)&ureg[0]  = *(const float4*)(eu + lane * 16);
  *(float4*)&ureg[4]  = *(const float4*)(eu + lane * 16 + 4);
  *(float4*)&ureg[8]  = *(const float4*)(eu + lane * 16 + 8);
  *(float4*)&ureg[12] = *(const float4*)(eu + lane * 16 + 12);
  float part = 0.f;
#pragma unroll
  for (int j = 0; j < 16; ++j) part += ureg[j] * ureg[j];
#pragma unroll
  for (int m = 1; m < 64; m <<= 1) part += __shfl_xor(part, m, 64);
  const float unorm = fmaxf(sqrtf(part), 1e-8f);

  u32 hPk[32];    // packed bf16 h: hPk[t*8 + sub*4 + (j>>1)] = cols (jj, jj+1)

  for (int t = 0; t < 4; ++t) {
    const int a = t * 8 + wave;
    const long opflat = (((long)step * 32 + b) * 32 + a) * 2;
    const int opL = ops[opflat], opR = ops[opflat + 1];
    const _Float16* PLp = P + (size_t)(b_local * 256 + opL) * 5120;
    const _Float16* PRp = P + (size_t)(2048 + b_local * 256 + opR) * 5120;
    const u16* ccLr = chc + (size_t)(b * 256 + opL) * 1024;
    const u16* ccRr = chc + (size_t)(b * 256 + opR) * 1024;
    float dot = 0.f, nn = 0.f;
#pragma unroll
    for (int sub = 0; sub < 2; ++sub) {
      const int g8 = lane * 16 + sub * 8;
      h8 pre[5];
#pragma unroll
      for (int q = 0; q < 5; ++q)
        pre[q] = *(const h8*)(PLp + q * 1024 + g8) + *(const h8*)(PRp + q * 1024 + g8);
      const u16x8 cl = *(const u16x8*)(ccLr + g8);
      const u16x8 cr = *(const u16x8*)(ccRr + g8);
      u16x8 co;
      u32 lo = 0;
#pragma unroll
      for (int j = 0; j < 8; ++j) {
        const int jj = sub * 8 + j;
        float pi  = (float)pre[0][j];   // pre-scaled by -log2e
        float pfL = (float)pre[1][j];
        float pfR = (float)pre[2][j];
        float po  = (float)pre[3][j];
        float pu  = (float)pre[4][j];   // pre-scaled by +2*log2e
        float cv = sig2(pfL) * bf2f(cl[j]) + sig2(pfR) * bf2f(cr[j])
                 + sig2(pi) * tanh2(pu);
        float hv = sig2(po) * fast_tanh(cv);
        co[j] = f2bf(cv);
        if ((j & 1) == 0) lo = (u32)f2bf(hv);
        else hPk[t * 8 + sub * 4 + (j >> 1)] = lo | ((u32)f2bf(hv) << 16);
        dot += hv * ureg[jj];
        nn  += hv * hv;
      }
      *(u16x8*)(cS + a * 1024 + sub * 512 + lane * 8) = co;  // permuted, b128
    }
#pragma unroll
    for (int m = 1; m < 64; m <<= 1) {
      dot += __shfl_xor(dot, m, 64);
      nn  += __shfl_xor(nn, m, 64);
    }
    if (lane == 0) eS[a] = dot / (unorm * fmaxf(sqrtf(nn), 1e-8f));
  }
  __syncthreads();

  // softmax over 32 (from LDS broadcast reads)
  float w[32];
  float mx = -1e30f;
#pragma unroll
  for (int a = 0; a < 32; ++a) mx = fmaxf(mx, eS[a]);
  float S = 0.f;
#pragma unroll
  for (int a = 0; a < 32; ++a) { w[a] = __expf(eS[a] - mx); S += w[a]; }
  const float inv = 1.0f / S;

  // c combine: thread owns cols g0,g0+1; u32 column reads (2-way, free)
  const int g0 = tid * 2;
  const int p = ((g0 >> 3) & 1) * 512 + (g0 >> 4) * 8 + (g0 & 7);
  float sc0 = 0.f, sc1 = 0.f;
#pragma unroll
  for (int a = 0; a < 32; ++a) {
    const u32 cv = *(const u32*)(cS + a * 1024 + p);
    sc0 += w[a] * __uint_as_float(cv << 16);
    sc1 += w[a] * __uint_as_float(cv & 0xffff0000u);
  }
  float* orow = out + ((size_t)b * CHART_ROWS + 256 + step) * 2048;
  *(float2*)(orow + g0) = make_float2(sc0 * inv, sc1 * inv);
  __syncthreads();            // all cS reads done; buffer reused below

  // h partials: thread sums its 4 a-rows for its 16 cols, stash to LDS
  float* rS = (float*)cS;     // [wave][1024] floats, swizzled for b128 writes
  float ph[16];
#pragma unroll
  for (int jj = 0; jj < 16; ++jj) ph[jj] = 0.f;
#pragma unroll
  for (int t = 0; t < 4; ++t) {
    const float wa = w[t * 8 + wave];
#pragma unroll
    for (int k = 0; k < 8; ++k) {
      const u32 pk2 = hPk[t * 8 + k];
      const int jj0 = (k >> 2) * 8 + (k & 3) * 2;
      ph[jj0]     += wa * __uint_as_float(pk2 << 16);
      ph[jj0 + 1] += wa * __uint_as_float(pk2 & 0xffff0000u);
    }
  }
#pragma unroll
  for (int s = 0; s < 4; ++s) {
    float4 v = make_float4(ph[s * 4], ph[s * 4 + 1], ph[s * 4 + 2], ph[s * 4 + 3]);
    // col g = l*16 + s*4 + k stored at word wave*1024 + s*256 + l*4 + k
    *(float4*)(rS + wave * 1024 + s * 256 + lane * 4) = v;   // lane-contiguous
  }
  __syncthreads();

  // reduce 8 wave-partials for cols g0,g0+1
  const int l_own = g0 >> 4, s_ = (g0 >> 2) & 3, k_ = g0 & 3;
  float sh0 = 0.f, sh1 = 0.f;
#pragma unroll
  for (int w8 = 0; w8 < 8; ++w8) {
    const float2 v = *(const float2*)(rS + w8 * 1024 + s_ * 256 + l_own * 4 + k_);
    sh0 += v.x; sh1 += v.y;
  }
  *(float2*)(orow + 1024 + g0) = make_float2(sh0 * inv, sh1 * inv);
}

extern "C" void kernel_launch(void* const* d_in, const int* in_sizes, int n_in,
                              void* d_out, int out_size, void* d_ws, size_t ws_size,
                              hipStream_t stream) {
  (void)in_sizes; (void)n_in; (void)out_size; (void)ws_size;
  const float* chart = (const float*)d_in[0];
  const int*   ops   = (const int*)d_in[1];
  // d_in[2] = start_index (256, hard-coded)
  const float* U     = (const float*)d_in[3];
  const float* bias  = (const float*)d_in[4];
  const float* eu    = (const float*)d_in[5];
  float* out = (float*)d_out;
  char* ws = (char*)d_ws;

  u16*      Ubf = (u16*)ws;                       // 20,971,520 B
  u16*      chb = (u16*)(ws + 20971520);          // 16,777,216 B
  u16*      chc = (u16*)(ws + 37748736);          // 16,777,216 B
  _Float16* P   = (_Float16*)(ws + 54525952);     // 41,943,040 B -> total 96,468,992 B

  k_cvt_u<<<10240, 256, 0, stream>>>((const float4*)U, Ubf);
  k_cvt_chart<<<8192, 256, 0, stream>>>(chart, chb, chc, out);

  for (int bg = 0; bg < 4; ++bg) {                  // 8 batches per group
    k_gemm_p<<<dim3(40, 32), 256, 0, stream>>>(chb, Ubf, bias, P, bg);
    k_fused<<<1024, 512, 0, stream>>>(chc, P, ops, eu, out, bg);
  }
}